// Round 6
// baseline (578.707 us; speedup 1.0000x reference)
//
#include <hip/hip_runtime.h>

#define IN_DIM 128
#define OUT_DIM 64
#define CAP 32
#define GRID_MAIN 512

typedef __attribute__((address_space(1))) const void gvoid_t;
typedef __attribute__((address_space(3))) void lvoid_t;

// ---- Build: fixed-capacity buckets (no scan, no chase). cursor[] zeroed
// via hipMemsetAsync. cursor[P] doubles as the overflow counter. ----
__global__ void scatter_kernel(const int* __restrict__ idx,
                               int* __restrict__ cursor,    // [P+1], pre-zeroed
                               int* __restrict__ bucket,    // [P*CAP]
                               int* __restrict__ overflow,  // [E]
                               int E, int P) {
    int e = blockIdx.x * 256 + threadIdx.x;
    if (e < E) {
        int p = idx[e];
        int pos = atomicAdd(&cursor[p], 1);
        if (pos < CAP) bucket[p * CAP + pos] = e;
        else           overflow[atomicAdd(&cursor[P], 1)] = e;
    }
}

// ---- Main: 512 blocks x ~20 pool entries each, producer/consumer pipelined.
// Wave 0 stages entry t+1's W (32 KB) into buf[(t+1)&1] via global_load_lds
// (width=16, XOR-pre-swizzled SOURCE, linear LDS dest — R4/R5-proven layout);
// waves 1-3 compute entry t from buf[t&1]. The __syncthreads at loop top
// drains the producer's vmcnt, so the buffer is ready exactly when consumers
// need it — staging of t+1 overlaps compute of t with no counted vmcnt. ----
__global__ __launch_bounds__(256) void pool_pipeline_kernel(
    const float* __restrict__ x,        // [E,128]
    const float* __restrict__ Wpool,    // [P,64,128]
    const float* __restrict__ bpool,    // [P,64]
    float*       __restrict__ out,      // [E,64]
    const int*   __restrict__ cursor,   // [P+1]
    const int*   __restrict__ bucket,   // [P*CAP]
    int P)
{
    __shared__ float Wbuf[2][OUT_DIM * IN_DIM];   // 2 x 32 KB = 64 KB static

    const int b    = blockIdx.x;
    const int G    = gridDim.x;
    const int wv   = threadIdx.x >> 6;
    const int lane = threadIdx.x & 63;

    const int T = (P > b) ? ((P - b + G - 1) / G) : 0;
    if (T == 0) return;                            // uniform per block

    // Stage one entry's W: 32 x global_load_lds, 1 KB each. LDS slot
    // s = j*64 + lane holds W[o][i4 ^ (o&7)] (o = s>>5, i4 = s&31).
    auto stage = [&](int p, int sel) {
        const float* Wp = Wpool + (size_t)p * (OUT_DIM * IN_DIM);
        char* base = (char*)&Wbuf[sel][0];
        #pragma unroll
        for (int j = 0; j < 32; ++j) {
            const int o  = (j << 1) + (lane >> 5);
            const int i4 = lane & 31;
            const float* g = Wp + o * IN_DIM + ((i4 ^ (o & 7)) << 2);
            __builtin_amdgcn_global_load_lds((gvoid_t*)g,
                                             (lvoid_t*)(base + (j << 10)), 16, 0, 0);
        }
    };

    if (wv == 0) stage(b, 0);                      // prologue

    for (int t = 0; t < T; ++t) {
        __syncthreads();                           // drains producer's stage of p_t
        const int pc = b + t * G;
        if (wv == 0) {
            const int pn = pc + G;
            if (pn < P) stage(pn, (t + 1) & 1);    // prefetch next entry
        } else {
            int n = cursor[pc];
            n = (n > CAP) ? CAP : n;
            if (n > 0) {
                const int sel = t & 1;
                const char* wbase = (const char*)&Wbuf[sel][0];
                const float bv = bpool[(size_t)pc * OUT_DIM + lane];
                const int cw = wv - 1;             // 0..2, 3 consumer waves
                for (int j = cw; j < n; j += 3) {
                    int e = bucket[pc * CAP + j];
                    e = __builtin_amdgcn_readfirstlane(e);   // wave-uniform
                    const float4* xg = reinterpret_cast<const float4*>(
                        x + (size_t)e * IN_DIM);
                    float ax = 0.f, ay = 0.f, az = 0.f, aw = 0.f;
                    #pragma unroll
                    for (int i4 = 0; i4 < 32; ++i4) {
                        const float4 w = *reinterpret_cast<const float4*>(
                            wbase + (lane << 9) + ((i4 ^ (lane & 7)) << 4));
                        const float4 xq = xg[i4];  // uniform-addr broadcast
                        ax += w.x * xq.x;
                        ay += w.y * xq.y;
                        az += w.z * xq.z;
                        aw += w.w * xq.w;
                    }
                    out[(size_t)e * OUT_DIM + lane] =
                        fmaxf((ax + ay) + (az + aw) + bv, 0.f);
                }
            }
        }
    }
}

// ---- Overflow fallback (bucket fuller than CAP — statistically empty for
// this input, but correct in principle). One wave per overflow edge. ----
__global__ void overflow_kernel(const float* __restrict__ x,
                                const float* __restrict__ Wpool,
                                const float* __restrict__ bpool,
                                float* __restrict__ out,
                                const int* __restrict__ cursor,
                                const int* __restrict__ overflow,
                                const int* __restrict__ idx, int P, int E) {
    int nov = cursor[P];
    nov = (nov < E) ? nov : E;
    const int lane = threadIdx.x & 63;
    const int wv = (blockIdx.x * blockDim.x + threadIdx.x) >> 6;
    const int nw = (gridDim.x * blockDim.x) >> 6;
    for (int w = wv; w < nov; w += nw) {
        const int e = overflow[w];
        const int p = idx[e];
        const float* Wrow = Wpool + (size_t)p * (OUT_DIM * IN_DIM)
                                  + (size_t)lane * IN_DIM;
        const float* xe = x + (size_t)e * IN_DIM;
        float acc = 0.f;
        #pragma unroll 8
        for (int i = 0; i < IN_DIM; i += 4) {
            const float4 wq = *reinterpret_cast<const float4*>(Wrow + i);
            const float4 xq = *reinterpret_cast<const float4*>(xe + i);
            acc += wq.x * xq.x + wq.y * xq.y + wq.z * xq.z + wq.w * xq.w;
        }
        acc += bpool[(size_t)p * OUT_DIM + lane];
        out[(size_t)e * OUT_DIM + lane] = fmaxf(acc, 0.f);
    }
}

extern "C" void kernel_launch(void* const* d_in, const int* in_sizes, int n_in,
                              void* d_out, int out_size, void* d_ws, size_t ws_size,
                              hipStream_t stream) {
    const float* x    = (const float*)d_in[0];   // [E,128,1]
    const int*   idx  = (const int*)d_in[1];     // [E]
    const float* W    = (const float*)d_in[2];   // [P,64,128]
    const float* b    = (const float*)d_in[3];   // [P,64,1]
    float* out = (float*)d_out;                  // [E,64,1] fp32

    const int E = in_sizes[1];
    const int P = in_sizes[2] / (OUT_DIM * IN_DIM);

    int* cursor   = (int*)d_ws;                  // P+1 (last = overflow count)
    int* bucket   = cursor + (P + 1);            // P*CAP
    int* overflow = bucket + (size_t)P * CAP;    // E

    hipMemsetAsync(cursor, 0, (size_t)(P + 1) * sizeof(int), stream);
    scatter_kernel<<<(E + 255) / 256, 256, 0, stream>>>(idx, cursor, bucket,
                                                        overflow, E, P);
    pool_pipeline_kernel<<<GRID_MAIN, 256, 0, stream>>>(x, W, b, out,
                                                        cursor, bucket, P);
    overflow_kernel<<<8, 256, 0, stream>>>(x, W, b, out, cursor, overflow,
                                           idx, P, E);
}